// Round 2
// baseline (351.520 us; speedup 1.0000x reference)
//
#include <hip/hip_runtime.h>
#include <stdint.h>

#define NB 16
#define CC 32
#define HH 224
#define WW 224
#define HWP (HH*WW)          // 50176
#define NHWP (NB*HWP)        // 802816

// workspace layout (bytes)
#define OFF_S1   0u
#define OFF_S2   3211264u
#define OFF_WP1  6422528u
#define OFF_WP2  6423680u
#define OFF_SQ1  6424832u    // 256 B (32 x u64)
#define OFF_SQ2  6425088u    // 256 B
#define OFF_SUM1 6425344u    // 128 B (32 x i32)
#define OFF_SUM2 6425472u    // 128 B
#define OFF_A1   6425600u
#define OFF_D1   6425728u
#define OFF_A2   6425856u
#define OFF_D2   6425984u

// ---------------- zero the stats accumulators (768 B starting at OFF_SQ1) ----------------
__global__ void zero_stats_kernel(uint32_t* __restrict__ p) {
    if (threadIdx.x < 192) p[threadIdx.x] = 0u;
}

// ---------------- pack weight signs: wp[oc*9 + k] bit i = signbit(w[oc][i][k]) ----------------
__global__ void pack_w_kernel(const uint32_t* __restrict__ w1, const uint32_t* __restrict__ w2,
                              uint32_t* __restrict__ wp1, uint32_t* __restrict__ wp2) {
    int t = threadIdx.x;
    if (t >= 576) return;
    const uint32_t* w = (t < 288) ? w1 : w2;
    uint32_t* o = (t < 288) ? wp1 : wp2;
    int idx = (t < 288) ? t : t - 288;
    int oc = idx / 9, k = idx - oc * 9;
    uint32_t word = 0;
    for (int i = 0; i < 32; ++i)
        word |= (w[(oc * 32 + i) * 9 + k] >> 31) << i;
    o[idx] = word;
}

// ---------------- pack activation signs: sp[n*HWP + p] bit c = signbit(x[n,c,p]) ----------------
__global__ void __launch_bounds__(256) pack_x_kernel(const uint32_t* __restrict__ x,
                                                     uint32_t* __restrict__ sp) {
    int t = blockIdx.x * 256 + threadIdx.x;        // 0..200703, 4 pixels per thread
    int n = t / (HWP / 4);
    int rem4 = t - n * (HWP / 4);
    const uint32_t* xp = x + (size_t)n * CC * HWP + (size_t)rem4 * 4;
    uint32_t w0 = 0, w1 = 0, w2 = 0, w3 = 0;
    #pragma unroll
    for (int c = 0; c < 32; ++c) {
        uint4 v = *reinterpret_cast<const uint4*>(xp + (size_t)c * HWP);
        w0 |= (v.x >> 31) << c;
        w1 |= (v.y >> 31) << c;
        w2 |= (v.z >> 31) << c;
        w3 |= (v.w >> 31) << c;
    }
    *reinterpret_cast<uint4*>(sp + (size_t)n * HWP + (size_t)rem4 * 4) =
        make_uint4(w0, w1, w2, w3);
}

// ---------------- 3x3 tap load with zero-pad masks ----------------
__device__ __forceinline__ void load_taps(const uint32_t* __restrict__ sp, int p,
                                          uint32_t a[9], uint32_t m[9], int& v32) {
    int n = p / HWP;
    int rem = p - n * HWP;
    int r = rem / WW;
    int cw = rem - r * WW;
    const uint32_t* img = sp + (size_t)n * HWP;
    v32 = 0;
    #pragma unroll
    for (int dh = -1; dh <= 1; ++dh) {
        int rr = r + dh;
        int rrc = min(max(rr, 0), HH - 1);
        bool rv = (unsigned)rr < (unsigned)HH;
        #pragma unroll
        for (int dw = -1; dw <= 1; ++dw) {
            int cc = cw + dw;
            int ccc = min(max(cc, 0), WW - 1);
            bool cv = (unsigned)cc < (unsigned)WW;
            int ti = (dh + 1) * 3 + (dw + 1);
            a[ti] = img[rrc * WW + ccc];   // clamped address, mask kills contribution
            bool valid = rv && cv;
            m[ti] = valid ? 0xFFFFFFFFu : 0u;
            v32 += valid ? 32 : 0;
        }
    }
}

__device__ __forceinline__ int conv_oc(const uint32_t a[9], const uint32_t m[9],
                                       int v32, const uint32_t* __restrict__ wp, int oc) {
    int pc = 0;
    #pragma unroll
    for (int t = 0; t < 9; ++t)
        pc += __popc((a[t] ^ wp[oc * 9 + t]) & m[t]);
    return v32 - 2 * pc;    // exact integer conv of +/-1 inputs with zero padding
}

// ---------------- conv + exact per-channel sum / sumsq ----------------
__global__ void __launch_bounds__(256) conv_stats_kernel(const uint32_t* __restrict__ sp,
                                                         const uint32_t* __restrict__ wp,
                                                         int* __restrict__ g_sum,
                                                         unsigned long long* __restrict__ g_sq) {
    const int PX = 8;
    int base = blockIdx.x * (256 * PX) + threadIdx.x;
    int acc_s[32], acc_q[32];
    #pragma unroll
    for (int i = 0; i < 32; ++i) { acc_s[i] = 0; acc_q[i] = 0; }
    for (int k = 0; k < PX; ++k) {
        int p = base + k * 256;
        uint32_t a[9], m[9]; int v32;
        load_taps(sp, p, a, m, v32);
        #pragma unroll
        for (int oc = 0; oc < 32; ++oc) {
            int c = conv_oc(a, m, v32, wp, oc);
            acc_s[oc] += c;
            acc_q[oc] += c * c;
        }
    }
    #pragma unroll
    for (int oc = 0; oc < 32; ++oc) {
        #pragma unroll
        for (int off = 32; off > 0; off >>= 1) {
            acc_s[oc] += __shfl_xor(acc_s[oc], off, 64);
            acc_q[oc] += __shfl_xor(acc_q[oc], off, 64);
        }
    }
    __shared__ int ls[4][32], lq[4][32];
    int lane = threadIdx.x & 63, wid = threadIdx.x >> 6;
    if (lane == 0) {
        #pragma unroll
        for (int oc = 0; oc < 32; ++oc) { ls[wid][oc] = acc_s[oc]; lq[wid][oc] = acc_q[oc]; }
    }
    __syncthreads();
    if (threadIdx.x < 32) {
        int s = ls[0][threadIdx.x] + ls[1][threadIdx.x] + ls[2][threadIdx.x] + ls[3][threadIdx.x];
        int q = lq[0][threadIdx.x] + lq[1][threadIdx.x] + lq[2][threadIdx.x] + lq[3][threadIdx.x];
        atomicAdd(&g_sum[threadIdx.x], s);
        atomicAdd(&g_sq[threadIdx.x], (unsigned long long)(long long)q);
    }
}

// ---------------- fold BN into per-channel affine y = a*c + d (exact int stats) ----------------
__global__ void bn_params_kernel(const int* __restrict__ g_sum,
                                 const unsigned long long* __restrict__ g_sq,
                                 const float* __restrict__ gamma,
                                 const float* __restrict__ beta,
                                 float* __restrict__ av, float* __restrict__ dv) {
    int c = threadIdx.x;
    if (c >= CC) return;
    double M = (double)NHWP;
    double mean = (double)g_sum[c] / M;
    double ex2 = (double)(long long)g_sq[c] / M;
    double var = ex2 - mean * mean;
    double inv = 1.0 / sqrt(var + 1e-5);
    double aa = inv * (double)gamma[c];
    av[c] = (float)aa;
    dv[c] = (float)((double)beta[c] - aa * mean);
}

// ---------------- conv1 again + BN1 + sign -> packed s2 ----------------
__global__ void __launch_bounds__(256) conv_bn_sign_kernel(const uint32_t* __restrict__ sp,
                                                           const uint32_t* __restrict__ wp,
                                                           const float* __restrict__ av,
                                                           const float* __restrict__ dv,
                                                           uint32_t* __restrict__ op) {
    int p = blockIdx.x * 256 + threadIdx.x;
    uint32_t a[9], m[9]; int v32;
    load_taps(sp, p, a, m, v32);
    uint32_t word = 0;
    #pragma unroll
    for (int oc = 0; oc < 32; ++oc) {
        int c = conv_oc(a, m, v32, wp, oc);
        float y = fmaf(av[oc], (float)c, dv[oc]);
        word |= (y < 0.0f ? 1u : 0u) << oc;
    }
    op[p] = word;
}

// ---------------- conv2 again + BN2 + residual add -> f32 out ----------------
__global__ void __launch_bounds__(256) conv_bn_res_kernel(const uint32_t* __restrict__ sp,
                                                          const uint32_t* __restrict__ wp,
                                                          const float* __restrict__ av,
                                                          const float* __restrict__ dv,
                                                          const float* __restrict__ x,
                                                          float* __restrict__ out) {
    int p = blockIdx.x * 256 + threadIdx.x;
    uint32_t a[9], m[9]; int v32;
    load_taps(sp, p, a, m, v32);
    int n = p / HWP;
    int rem = p - n * HWP;
    const float* xp = x + (size_t)n * CC * HWP + rem;
    float* op = out + (size_t)n * CC * HWP + rem;
    #pragma unroll
    for (int oc = 0; oc < 32; ++oc) {
        int c = conv_oc(a, m, v32, wp, oc);
        float y = fmaf(av[oc], (float)c, dv[oc]);
        op[(size_t)oc * HWP] = xp[(size_t)oc * HWP] + y;
    }
}

extern "C" void kernel_launch(void* const* d_in, const int* in_sizes, int n_in,
                              void* d_out, int out_size, void* d_ws, size_t ws_size,
                              hipStream_t stream) {
    const float* x  = (const float*)d_in[0];
    const float* w1 = (const float*)d_in[1];
    const float* g1 = (const float*)d_in[2];
    const float* b1 = (const float*)d_in[3];
    const float* w2 = (const float*)d_in[4];
    const float* g2 = (const float*)d_in[5];
    const float* b2 = (const float*)d_in[6];
    float* out = (float*)d_out;

    char* ws = (char*)d_ws;
    uint32_t* s1  = (uint32_t*)(ws + OFF_S1);
    uint32_t* s2  = (uint32_t*)(ws + OFF_S2);
    uint32_t* wp1 = (uint32_t*)(ws + OFF_WP1);
    uint32_t* wp2 = (uint32_t*)(ws + OFF_WP2);
    unsigned long long* sq1 = (unsigned long long*)(ws + OFF_SQ1);
    unsigned long long* sq2 = (unsigned long long*)(ws + OFF_SQ2);
    int* sum1 = (int*)(ws + OFF_SUM1);
    int* sum2 = (int*)(ws + OFF_SUM2);
    float* a1 = (float*)(ws + OFF_A1);
    float* d1 = (float*)(ws + OFF_D1);
    float* a2 = (float*)(ws + OFF_A2);
    float* d2 = (float*)(ws + OFF_D2);

    zero_stats_kernel<<<1, 256, 0, stream>>>((uint32_t*)(ws + OFF_SQ1));
    pack_w_kernel<<<1, 576, 0, stream>>>((const uint32_t*)w1, (const uint32_t*)w2, wp1, wp2);
    pack_x_kernel<<<784, 256, 0, stream>>>((const uint32_t*)x, s1);
    conv_stats_kernel<<<392, 256, 0, stream>>>(s1, wp1, sum1, sq1);
    bn_params_kernel<<<1, 64, 0, stream>>>(sum1, sq1, g1, b1, a1, d1);
    conv_bn_sign_kernel<<<3136, 256, 0, stream>>>(s1, wp1, a1, d1, s2);
    conv_stats_kernel<<<392, 256, 0, stream>>>(s2, wp2, sum2, sq2);
    bn_params_kernel<<<1, 64, 0, stream>>>(sum2, sq2, g2, b2, a2, d2);
    conv_bn_res_kernel<<<3136, 256, 0, stream>>>(s2, wp2, a2, d2, x, out);
}

// Round 3
// 348.467 us; speedup vs baseline: 1.0088x; 1.0088x over previous
//
#include <hip/hip_runtime.h>
#include <stdint.h>

#define NB 16
#define CC 32
#define HH 224
#define WW 224
#define HWP (HH*WW)          // 50176
#define NHWP (NB*HWP)        // 802816
#define PW 226
#define PSZ (PW*PW)          // 51076 padded words per image

// workspace layout (bytes)
#define OFF_S1   0u
#define OFF_S2   3268864u    // 16*51076*4
#define OFF_WP1  6537728u
#define OFF_WP2  6538880u
#define OFF_SQ1  6540032u    // 32 x u64
#define OFF_SQ2  6540288u    // 32 x u64
#define OFF_SUM1 6540544u    // 32 x i32
#define OFF_SUM2 6540672u    // 32 x i32

// ============ setup: pack weights, zero stats, zero pad borders of s1/s2 ============
__global__ void __launch_bounds__(256) k_setup(const uint32_t* __restrict__ w1,
                                               const uint32_t* __restrict__ w2,
                                               char* __restrict__ ws) {
    int t = blockIdx.x * 256 + threadIdx.x;
    if (t < 576) {
        const uint32_t* w = (t < 288) ? w1 : w2;
        uint32_t* o = (uint32_t*)(ws + ((t < 288) ? OFF_WP1 : OFF_WP2));
        int idx = (t < 288) ? t : t - 288;
        int oc = idx / 9, k = idx - oc * 9;
        uint32_t word = 0;
        for (int i = 0; i < 32; ++i)
            word |= (w[(oc * 32 + i) * 9 + k] >> 31) << i;
        o[idx] = word;
    } else if (t < 768) {
        ((uint32_t*)(ws + OFF_SQ1))[t - 576] = 0u;   // 192 words: sq1,sq2,sum1,sum2
    } else if (t >= 1024 && t < 1024 + 28800) {
        int b = t - 1024;
        uint32_t* buf = (uint32_t*)(ws + ((b < 14400) ? OFF_S1 : OFF_S2));
        int bb = (b < 14400) ? b : b - 14400;
        int n = bb / 900;
        int e = bb - n * 900;
        int row, col;
        if (e < 226)      { row = 0;   col = e; }
        else if (e < 452) { row = 225; col = e - 226; }
        else { int k = e - 452; row = 1 + (k >> 1); col = (k & 1) ? 225 : 0; }
        buf[(size_t)n * PSZ + row * PW + col] = 0u;
    }
}

// ============ pack activation signs into padded layout ============
__global__ void __launch_bounds__(256) k_packx(const uint32_t* __restrict__ x,
                                               uint32_t* __restrict__ sp) {
    int t = blockIdx.x * 256 + threadIdx.x;        // 16 * 12544 threads, 4 px each
    int n = t / (HWP / 4);
    int rem4 = t - n * (HWP / 4);
    int px0 = rem4 * 4;
    int r = px0 / WW;
    int cw0 = px0 - r * WW;                        // row-aligned: 224 % 4 == 0
    const uint32_t* xp = x + (size_t)n * CC * HWP + px0;
    uint32_t w0 = 0, w1 = 0, w2 = 0, w3 = 0;
    #pragma unroll
    for (int c = 0; c < 32; ++c) {
        uint4 v = *reinterpret_cast<const uint4*>(xp + (size_t)c * HWP);
        w0 |= (v.x >> 31) << c;
        w1 |= (v.y >> 31) << c;
        w2 |= (v.z >> 31) << c;
        w3 |= (v.w >> 31) << c;
    }
    uint32_t* op = sp + (size_t)n * PSZ + (r + 1) * PW + (cw0 + 1);
    op[0] = w0; op[1] = w1; op[2] = w2; op[3] = w3;
}

// ============ border-correction table: C[ty][oc] = sum over pad taps of (32 - 2*popc(w)) ============
__device__ __forceinline__ void build_ctab(const uint32_t* __restrict__ wp, int (*Ctab)[32]) {
    for (int i = threadIdx.x; i < 512; i += 256) {
        int ty = i >> 5, oc = i & 31;
        int s = 0;
        #pragma unroll
        for (int t = 0; t < 9; ++t) {
            int dh = t / 3 - 1, dw = t % 3 - 1;
            bool pad = ((ty & 1) && dh < 0) || ((ty & 2) && dh > 0) ||
                       ((ty & 4) && dw < 0) || ((ty & 8) && dw > 0);
            if (pad) s += 32 - 2 * __popc(wp[oc * 9 + t]);
        }
        Ctab[ty][oc] = s;
    }
}

__device__ __forceinline__ void decode_px(int p, int& n, int& r, int& cw) {
    n = p / HWP;
    int rem = p - n * HWP;
    r = rem / WW;
    cw = rem - r * WW;
}

#define LOAD_TAPS(base, a)                                             \
    uint32_t a##0 = (base)[-PW - 1], a##1 = (base)[-PW], a##2 = (base)[-PW + 1], \
             a##3 = (base)[-1],      a##4 = (base)[0],   a##5 = (base)[1],       \
             a##6 = (base)[PW - 1],  a##7 = (base)[PW],  a##8 = (base)[PW + 1];

#define CONV_PC(a, wb)                                                  \
    (__popc(a##0 ^ (wb)[0]) + __popc(a##1 ^ (wb)[1]) + __popc(a##2 ^ (wb)[2]) + \
     __popc(a##3 ^ (wb)[3]) + __popc(a##4 ^ (wb)[4]) + __popc(a##5 ^ (wb)[5]) + \
     __popc(a##6 ^ (wb)[6]) + __popc(a##7 ^ (wb)[7]) + __popc(a##8 ^ (wb)[8]))

// ============ conv + exact per-channel sum / sumsq ============
__global__ void __launch_bounds__(256) k_stats(const uint32_t* __restrict__ sp,
                                               const uint32_t* __restrict__ wp,
                                               int* __restrict__ g_sum,
                                               unsigned long long* __restrict__ g_sq) {
    __shared__ int Ctab[16][32];
    build_ctab(wp, Ctab);
    __syncthreads();

    int acc_s[32], acc_q[32];
    #pragma unroll
    for (int i = 0; i < 32; ++i) { acc_s[i] = 0; acc_q[i] = 0; }

    #pragma unroll
    for (int k = 0; k < 4; ++k) {
        int p = blockIdx.x * 1024 + k * 256 + threadIdx.x;
        int n, r, cw; decode_px(p, n, r, cw);
        const uint32_t* base = sp + (size_t)n * PSZ + (r + 1) * PW + (cw + 1);
        LOAD_TAPS(base, a)
        int ty = (r == 0 ? 1 : 0) | (r == HH - 1 ? 2 : 0) |
                 (cw == 0 ? 4 : 0) | (cw == WW - 1 ? 8 : 0);
        bool anyb = __any(ty != 0);
        #pragma unroll
        for (int oc = 0; oc < 32; ++oc) {
            const uint32_t* wb = wp + oc * 9;
            int pc = CONV_PC(a, wb);
            int c = 288 - 2 * pc;
            if (anyb) c -= Ctab[ty][oc];
            acc_s[oc] += c;
            acc_q[oc] += c * c;
        }
    }

    #pragma unroll
    for (int oc = 0; oc < 32; ++oc) {
        #pragma unroll
        for (int off = 32; off > 0; off >>= 1) {
            acc_s[oc] += __shfl_xor(acc_s[oc], off, 64);
            acc_q[oc] += __shfl_xor(acc_q[oc], off, 64);
        }
    }
    __shared__ int ls[4][32], lq[4][32];
    int lane = threadIdx.x & 63, wid = threadIdx.x >> 6;
    if (lane == 0) {
        #pragma unroll
        for (int oc = 0; oc < 32; ++oc) { ls[wid][oc] = acc_s[oc]; lq[wid][oc] = acc_q[oc]; }
    }
    __syncthreads();
    if (threadIdx.x < 32) {
        int s = ls[0][threadIdx.x] + ls[1][threadIdx.x] + ls[2][threadIdx.x] + ls[3][threadIdx.x];
        int q = lq[0][threadIdx.x] + lq[1][threadIdx.x] + lq[2][threadIdx.x] + lq[3][threadIdx.x];
        atomicAdd(&g_sum[threadIdx.x], s);
        atomicAdd(&g_sq[threadIdx.x], (unsigned long long)(long long)q);
    }
}

// ============ per-block BN affine from exact int stats ============
__device__ __forceinline__ void build_affine(const int* __restrict__ g_sum,
                                             const unsigned long long* __restrict__ g_sq,
                                             const float* __restrict__ gamma,
                                             const float* __restrict__ beta,
                                             float* aL, float* dL) {
    if (threadIdx.x < 32) {
        int c = threadIdx.x;
        double M = (double)NHWP;
        double mean = (double)g_sum[c] / M;
        double ex2 = (double)(long long)g_sq[c] / M;
        double var = ex2 - mean * mean;
        double inv = 1.0 / sqrt(var + 1e-5);
        double aa = inv * (double)gamma[c];
        aL[c] = (float)aa;
        dL[c] = (float)((double)beta[c] - aa * mean);
    }
}

// ============ conv1 + BN1 + sign -> packed padded s2 ============
__global__ void __launch_bounds__(256) k_sign(const uint32_t* __restrict__ sp,
                                              const uint32_t* __restrict__ wp,
                                              const int* __restrict__ g_sum,
                                              const unsigned long long* __restrict__ g_sq,
                                              const float* __restrict__ gamma,
                                              const float* __restrict__ beta,
                                              uint32_t* __restrict__ op) {
    __shared__ int Ctab[16][32];
    __shared__ float aL[32], dL[32];
    build_ctab(wp, Ctab);
    build_affine(g_sum, g_sq, gamma, beta, aL, dL);
    __syncthreads();

    int p = blockIdx.x * 256 + threadIdx.x;
    int n, r, cw; decode_px(p, n, r, cw);
    const uint32_t* base = sp + (size_t)n * PSZ + (r + 1) * PW + (cw + 1);
    LOAD_TAPS(base, a)
    int ty = (r == 0 ? 1 : 0) | (r == HH - 1 ? 2 : 0) |
             (cw == 0 ? 4 : 0) | (cw == WW - 1 ? 8 : 0);
    bool anyb = __any(ty != 0);
    uint32_t word = 0;
    #pragma unroll
    for (int oc = 0; oc < 32; ++oc) {
        const uint32_t* wb = wp + oc * 9;
        int pc = CONV_PC(a, wb);
        int c = 288 - 2 * pc;
        if (anyb) c -= Ctab[ty][oc];
        float y = fmaf(aL[oc], (float)c, dL[oc]);
        word |= (y < 0.0f ? 1u : 0u) << oc;
    }
    op[(size_t)n * PSZ + (r + 1) * PW + (cw + 1)] = word;
}

// ============ conv2 + BN2 + residual -> f32 out ============
__global__ void __launch_bounds__(256) k_res(const uint32_t* __restrict__ sp,
                                             const uint32_t* __restrict__ wp,
                                             const int* __restrict__ g_sum,
                                             const unsigned long long* __restrict__ g_sq,
                                             const float* __restrict__ gamma,
                                             const float* __restrict__ beta,
                                             const float* __restrict__ x,
                                             float* __restrict__ out) {
    __shared__ int Ctab[16][32];
    __shared__ float aL[32], dL[32];
    build_ctab(wp, Ctab);
    build_affine(g_sum, g_sq, gamma, beta, aL, dL);
    __syncthreads();

    int p = blockIdx.x * 256 + threadIdx.x;
    int n, r, cw; decode_px(p, n, r, cw);
    int rem = r * WW + cw;
    const uint32_t* base = sp + (size_t)n * PSZ + (r + 1) * PW + (cw + 1);
    LOAD_TAPS(base, a)
    int ty = (r == 0 ? 1 : 0) | (r == HH - 1 ? 2 : 0) |
             (cw == 0 ? 4 : 0) | (cw == WW - 1 ? 8 : 0);
    bool anyb = __any(ty != 0);
    const float* xp = x + (size_t)n * CC * HWP + rem;
    float* op = out + (size_t)n * CC * HWP + rem;
    #pragma unroll
    for (int oc = 0; oc < 32; ++oc) {
        const uint32_t* wb = wp + oc * 9;
        int pc = CONV_PC(a, wb);
        int c = 288 - 2 * pc;
        if (anyb) c -= Ctab[ty][oc];
        float y = fmaf(aL[oc], (float)c, dL[oc]);
        op[(size_t)oc * HWP] = xp[(size_t)oc * HWP] + y;
    }
}

extern "C" void kernel_launch(void* const* d_in, const int* in_sizes, int n_in,
                              void* d_out, int out_size, void* d_ws, size_t ws_size,
                              hipStream_t stream) {
    const float* x  = (const float*)d_in[0];
    const float* w1 = (const float*)d_in[1];
    const float* g1 = (const float*)d_in[2];
    const float* b1 = (const float*)d_in[3];
    const float* w2 = (const float*)d_in[4];
    const float* g2 = (const float*)d_in[5];
    const float* b2 = (const float*)d_in[6];
    float* out = (float*)d_out;

    char* ws = (char*)d_ws;
    uint32_t* s1  = (uint32_t*)(ws + OFF_S1);
    uint32_t* s2  = (uint32_t*)(ws + OFF_S2);
    uint32_t* wp1 = (uint32_t*)(ws + OFF_WP1);
    uint32_t* wp2 = (uint32_t*)(ws + OFF_WP2);
    unsigned long long* sq1 = (unsigned long long*)(ws + OFF_SQ1);
    unsigned long long* sq2 = (unsigned long long*)(ws + OFF_SQ2);
    int* sum1 = (int*)(ws + OFF_SUM1);
    int* sum2 = (int*)(ws + OFF_SUM2);

    k_setup<<<120, 256, 0, stream>>>((const uint32_t*)w1, (const uint32_t*)w2, ws);
    k_packx<<<784, 256, 0, stream>>>((const uint32_t*)x, s1);
    k_stats<<<784, 256, 0, stream>>>(s1, wp1, sum1, sq1);
    k_sign<<<3136, 256, 0, stream>>>(s1, wp1, sum1, sq1, g1, b1, s2);
    k_stats<<<784, 256, 0, stream>>>(s2, wp2, sum2, sq2);
    k_res<<<3136, 256, 0, stream>>>(s2, wp2, sum2, sq2, g2, b2, x, out);
}